// Round 7
// baseline (87.489 us; speedup 1.0000x reference)
//
#include <hip/hip_runtime.h>
#include <hip/hip_fp16.h>

// out[m][n] = fp16( fp16( (sum_k x[m][k]*w6[n][k]) * scale[n] ) + bias[n] ), stored fp32
// All inputs pushed as fp32 (fp16-exact values) -> cvt fp16 (exact), f16 MFMA, fp32 acc.
// Structure: split-K x4 -> 1024 blocks (4 blocks/CU, 32 waves/CU) for TLP-based latency
// hiding (m114). Partials atomicAdd'ed into d_out (zeroed per launch), finalize kernel
// applies scale/bias rounding.

typedef __attribute__((ext_vector_type(8))) _Float16 half8;
typedef __attribute__((ext_vector_type(2))) __fp16 fp16x2;  // cvt_pkrtz return type
typedef __attribute__((ext_vector_type(4))) float f32x4;

constexpr int K   = 4096;
constexpr int N   = 4096;
constexpr int MT  = 256;
constexpr int BM  = 64;
constexpr int BN  = 64;
constexpr int BK  = 128;
constexpr int SPL = 4;              // K splits
constexpr int KSPL = K / SPL;       // 1024 per block
constexpr int NTL  = KSPL / BK;     // 8 K-tiles per block
constexpr int LDH   = BK + 8;       // 136 halves = 272B row stride
constexpr int TILEH = 64 * LDH;     // halves per operand tile (17,408 B)
// lds: [op(2: A=x, B=w)][64][LDH] single-buffered = 34,816 B -> 4 blocks/CU

__device__ __forceinline__ void pack_store(_Float16* dst, float4 a, float4 b,
                                           float4 c, float4 d) {
    half8 h0, h1; fp16x2 p;
    p = __builtin_amdgcn_cvt_pkrtz(a.x, a.y); h0[0]=(_Float16)p[0]; h0[1]=(_Float16)p[1];
    p = __builtin_amdgcn_cvt_pkrtz(a.z, a.w); h0[2]=(_Float16)p[0]; h0[3]=(_Float16)p[1];
    p = __builtin_amdgcn_cvt_pkrtz(b.x, b.y); h0[4]=(_Float16)p[0]; h0[5]=(_Float16)p[1];
    p = __builtin_amdgcn_cvt_pkrtz(b.z, b.w); h0[6]=(_Float16)p[0]; h0[7]=(_Float16)p[1];
    p = __builtin_amdgcn_cvt_pkrtz(c.x, c.y); h1[0]=(_Float16)p[0]; h1[1]=(_Float16)p[1];
    p = __builtin_amdgcn_cvt_pkrtz(c.z, c.w); h1[2]=(_Float16)p[0]; h1[3]=(_Float16)p[1];
    p = __builtin_amdgcn_cvt_pkrtz(d.x, d.y); h1[4]=(_Float16)p[0]; h1[5]=(_Float16)p[1];
    p = __builtin_amdgcn_cvt_pkrtz(d.z, d.w); h1[6]=(_Float16)p[0]; h1[7]=(_Float16)p[1];
    *(half8*)(dst)     = h0;
    *(half8*)(dst + 8) = h1;
}

__global__ __launch_bounds__(512, 8)
void fp6lin_gemm(const float* __restrict__ X,
                 const float* __restrict__ W,
                 float* __restrict__ Oacc)
{
    __shared__ __align__(16) _Float16 lds[2 * TILEH];   // 34,816 B

    const int tid  = (int)threadIdx.x;
    const int lane = tid & 63;
    const int wid  = tid >> 6;          // 8 waves: 2 (M) x 4 (N), wave tile 32x16
    const int wm   = (wid & 1) * 32;
    const int wn   = (wid >> 1) * 16;

    // XCD swizzle: 1024 blocks / 8 XCDs = 128 each. Within an XCD, bm varies fastest,
    // so the 4 blocks sharing a W-chunk (same bn, same k-split) are co-located+co-timed.
    const int bid = (int)blockIdx.x;
    const int swz = (bid & 7) * 128 + (bid >> 3);
    const int bm  = (swz & 3) * BM;     // 4 M-tiles
    const int g   = swz >> 2;           // 0..255
    const int kb  = (g & 3) * KSPL;     // 4 K-splits
    const int bn  = (g >> 2) * BN;      // 64 N-tiles

    // staging: thread t -> row t>>3 (64 rows), 16 consecutive floats at col (t&7)*16
    const int srow = tid >> 3;
    const int scol = (tid & 7) * 16;
    const float* xp = X + (size_t)(bm + srow) * K + kb + scol;
    const float* wp = W + (size_t)(bn + srow) * K + kb + scol;
    _Float16* stA = lds + srow * LDH + scol;            // x tile
    _Float16* stB = lds + TILEH + srow * LDH + scol;    // w tile

    // frag read pointers (16x16x32 layout: row=lane&15, k=(lane>>4)*8+j)
    const _Float16* pa = lds + (wm + (lane & 15)) * LDH + ((lane >> 4) << 3);
    const _Float16* pb = lds + TILEH + (wn + (lane & 15)) * LDH + ((lane >> 4) << 3);

    f32x4 acc0 = {0.f, 0.f, 0.f, 0.f};
    f32x4 acc1 = {0.f, 0.f, 0.f, 0.f};

    // two named register tile-slots (no runtime indexing -> stays in VGPRs)
    float4 s0w0, s0w1, s0w2, s0w3, s0x0, s0x1, s0x2, s0x3;
    float4 s1w0, s1w1, s1w2, s1w3, s1x0, s1x1, s1x2, s1x3;

#define LOAD0(t) do { const float* q = wp + (t) * BK; const float* r = xp + (t) * BK; \
        s0w0 = *(const float4*)(q);      s0w1 = *(const float4*)(q + 4);             \
        s0w2 = *(const float4*)(q + 8);  s0w3 = *(const float4*)(q + 12);            \
        s0x0 = *(const float4*)(r);      s0x1 = *(const float4*)(r + 4);             \
        s0x2 = *(const float4*)(r + 8);  s0x3 = *(const float4*)(r + 12); } while (0)
#define LOAD1(t) do { const float* q = wp + (t) * BK; const float* r = xp + (t) * BK; \
        s1w0 = *(const float4*)(q);      s1w1 = *(const float4*)(q + 4);             \
        s1w2 = *(const float4*)(q + 8);  s1w3 = *(const float4*)(q + 12);            \
        s1x0 = *(const float4*)(r);      s1x1 = *(const float4*)(r + 4);             \
        s1x2 = *(const float4*)(r + 8);  s1x3 = *(const float4*)(r + 12); } while (0)
#define STORE0() do { pack_store(stA, s0x0, s0x1, s0x2, s0x3);          \
                      pack_store(stB, s0w0, s0w1, s0w2, s0w3); } while (0)
#define STORE1() do { pack_store(stA, s1x0, s1x1, s1x2, s1x3);          \
                      pack_store(stB, s1w0, s1w1, s1w2, s1w3); } while (0)
#define COMPUTE() do {                                                  \
        _Pragma("unroll")                                               \
        for (int kk = 0; kk < BK / 32; ++kk) {                          \
            half8 a0 = *(const half8*)(pa + kk * 32);                   \
            half8 a1 = *(const half8*)(pa + 16 * LDH + kk * 32);        \
            half8 b  = *(const half8*)(pb + kk * 32);                   \
            acc0 = __builtin_amdgcn_mfma_f32_16x16x32_f16(a0, b, acc0, 0, 0, 0); \
            acc1 = __builtin_amdgcn_mfma_f32_16x16x32_f16(a1, b, acc1, 0, 0, 0); \
        } } while (0)

    LOAD0(0);
    LOAD1(1);

    for (int t2 = 0; t2 < NTL; t2 += 2) {
        if (t2) __syncthreads();          // previous tile's readers done
        STORE0();                         // slot0 = tile t2 (loaded ~2 tiles ago)
        __syncthreads();
        if (t2 + 2 < NTL) LOAD0(t2 + 2);  // refill slot0, in flight over ~2 tiles
        COMPUTE();
        __syncthreads();
        STORE1();                         // slot1 = tile t2+1
        __syncthreads();
        if (t2 + 3 < NTL) LOAD1(t2 + 3);
        COMPUTE();
    }
#undef LOAD0
#undef LOAD1
#undef STORE0
#undef STORE1
#undef COMPUTE

    // partial-sum epilogue: C/D layout col=lane&15, row=(lane>>4)*4+reg [m89/m91]
    const int orow = bm + wm + ((lane >> 4) << 2);
    const int ocol = bn + wn + (lane & 15);
    #pragma unroll
    for (int r = 0; r < 4; ++r) {
        atomicAdd(&Oacc[(size_t)(orow + r) * N + ocol],      acc0[r]);
        atomicAdd(&Oacc[(size_t)(orow + 16 + r) * N + ocol], acc1[r]);
    }
}

// out = fp32( fp16( fp16(sum * scale[n]) + bias[n] ) ), in place over d_out
__global__ __launch_bounds__(256)
void fp6lin_finalize(float* __restrict__ O,
                     const float* __restrict__ S,
                     const float* __restrict__ Bi)
{
    const int i = ((int)blockIdx.x * 256 + (int)threadIdx.x) * 4;
    const int n = i & (N - 1);
    float4 v  = *(float4*)(O + i);
    float4 sc = *(const float4*)(S + n);
    float4 bb = *(const float4*)(Bi + n);
    v.x = (float)(_Float16)((float)(_Float16)(v.x * sc.x) + bb.x);
    v.y = (float)(_Float16)((float)(_Float16)(v.y * sc.y) + bb.y);
    v.z = (float)(_Float16)((float)(_Float16)(v.z * sc.z) + bb.z);
    v.w = (float)(_Float16)((float)(_Float16)(v.w * sc.w) + bb.w);
    *(float4*)(O + i) = v;
}

extern "C" void kernel_launch(void* const* d_in, const int* in_sizes, int n_in,
                              void* d_out, int out_size, void* d_ws, size_t ws_size,
                              hipStream_t stream) {
    const float* x  = (const float*)d_in[0];
    const float* w  = (const float*)d_in[1];
    const float* s  = (const float*)d_in[2];
    const float* bi = (const float*)d_in[3];
    float* o = (float*)d_out;

    hipMemsetAsync(o, 0, (size_t)out_size * sizeof(float), stream);
    fp6lin_gemm<<<dim3(4 * 64 * SPL), dim3(512), 0, stream>>>(x, w, o);
    fp6lin_finalize<<<dim3(MT * N / 4 / 256), dim3(256), 0, stream>>>(o, s, bi);
}

// Round 8
// 37.925 us; speedup vs baseline: 2.3069x; 2.3069x over previous
//
#include <hip/hip_runtime.h>
#include <hip/hip_fp16.h>

// out[m][n] = fp16( fp16( (sum_k x[m][k]*w6[n][k]) * scale[n] ) + bias[n] ), stored fp32
// Inputs pushed as fp32 (fp16-exact values) -> cvt fp16 (exact), f16 MFMA, fp32 acc.
// Structure: split-K x SPL, 256-thr blocks (4 waves, 64x64 tile), single-buffer LDS,
// 4 blocks/CU -> TLP latency hiding (m114). Partials STREAMED to d_ws (no atomics:
// round-7 showed atomic RMW amplification 16MB->250MB HBM). Reduce+finalize kernel.

typedef __attribute__((ext_vector_type(8))) _Float16 half8;
typedef __attribute__((ext_vector_type(4))) _Float16 half4;
typedef __attribute__((ext_vector_type(2))) __fp16 fp16x2;  // cvt_pkrtz return type
typedef __attribute__((ext_vector_type(4))) float f32x4;

constexpr int K  = 4096;
constexpr int N  = 4096;
constexpr int M  = 256;
constexpr int BM = 64;
constexpr int BN = 64;
constexpr int BK = 128;
constexpr int LDH   = BK + 8;       // 136 halves = 272B row stride
constexpr int TILEH = 64 * LDH;     // halves per operand tile (17,408 B)
// lds: [op(2: A=x, B=w)][64][LDH] single-buffered = 34,816 B -> 4 blocks/CU

__device__ __forceinline__ half4 pack4(float4 v) {
    fp16x2 p0 = __builtin_amdgcn_cvt_pkrtz(v.x, v.y);   // exact: inputs fp16-exact
    fp16x2 p1 = __builtin_amdgcn_cvt_pkrtz(v.z, v.w);
    half4 h;
    h[0] = (_Float16)p0[0]; h[1] = (_Float16)p0[1];
    h[2] = (_Float16)p1[0]; h[3] = (_Float16)p1[1];
    return h;
}

template <int SPL>
__global__ __launch_bounds__(256, 4)
void fp6lin_gemm(const float* __restrict__ X,
                 const float* __restrict__ W,
                 float* __restrict__ P)      // [SPL][M][N] fp32 partials
{
    constexpr int KSPL = K / SPL;
    constexpr int NTL  = KSPL / BK;
    constexpr int GRID = 4 * 64 * SPL;

    __shared__ __align__(16) _Float16 lds[2 * TILEH];

    const int tid  = (int)threadIdx.x;
    const int lane = tid & 63;
    const int wid  = tid >> 6;          // 4 waves: 2 (M) x 2 (N), wave tile 32x32
    const int wm   = (wid & 1) * 32;
    const int wn   = (wid >> 1) * 32;

    // XCD swizzle: bm varies fastest -> the 4 blocks sharing a W-chunk are
    // co-located on one XCD (W HBM-read once, 3 L2 hits).
    const int bid = (int)blockIdx.x;
    const int g   = (bid & 7) * (GRID / 8) + (bid >> 3);
    const int bm  = (g & 3) * BM;
    const int sp  = (g >> 2) % SPL;
    const int bn  = ((g >> 2) / SPL) * BN;
    const int kb  = sp * KSPL;

    const float* Xt = X + (size_t)bm * K + kb;
    const float* Wt = W + (size_t)bn * K + kb;

    // staging map (fully coalesced): load j covers tile floats [j*1024 + 4t .. +4):
    // wave instruction = 64 lanes x 16B contiguous = 1KB segment.
    const int r0 = tid >> 5;            // 0..7
    const int c0 = 4 * (tid & 31);      // 0..124

    // frag read pointers (16x16x32 layout: row=lane&15, k=(lane>>4)*8+j)
    const _Float16* pa = lds + (wm + (lane & 15)) * LDH + ((lane >> 4) << 3);
    const _Float16* pb = lds + TILEH + (wn + (lane & 15)) * LDH + ((lane >> 4) << 3);

    f32x4 acc00 = {0.f, 0.f, 0.f, 0.f};
    f32x4 acc10 = acc00, acc01 = acc00, acc11 = acc00;

    for (int t = 0; t < NTL; ++t) {
        if (t) __syncthreads();                 // previous tile's readers done
        const float* xa = Xt + t * BK;
        const float* wa = Wt + t * BK;
        #pragma unroll
        for (int j = 0; j < 8; ++j) {
            const int row = j * 8 + r0;
            float4 va = *(const float4*)(xa + (size_t)row * K + c0);
            float4 vb = *(const float4*)(wa + (size_t)row * K + c0);
            *(half4*)(lds + row * LDH + c0)         = pack4(va);
            *(half4*)(lds + TILEH + row * LDH + c0) = pack4(vb);
        }
        __syncthreads();

        #pragma unroll
        for (int kk = 0; kk < BK / 32; ++kk) {
            const _Float16* qa = pa + kk * 32;
            const _Float16* qb = pb + kk * 32;
            half8 a0 = *(const half8*)(qa);
            half8 a1 = *(const half8*)(qa + 16 * LDH);
            half8 b0 = *(const half8*)(qb);
            half8 b1 = *(const half8*)(qb + 16 * LDH);
            acc00 = __builtin_amdgcn_mfma_f32_16x16x32_f16(a0, b0, acc00, 0, 0, 0);
            acc10 = __builtin_amdgcn_mfma_f32_16x16x32_f16(a1, b0, acc10, 0, 0, 0);
            acc01 = __builtin_amdgcn_mfma_f32_16x16x32_f16(a0, b1, acc01, 0, 0, 0);
            acc11 = __builtin_amdgcn_mfma_f32_16x16x32_f16(a1, b1, acc11, 0, 0, 0);
        }
    }

    // streamed partial stores (no atomics). C/D: col=lane&15, row=(lane>>4)*4+reg.
    float* Pb = P + (size_t)sp * M * N;
    const int orow = bm + wm + ((lane >> 4) << 2);
    const int ocol = bn + wn + (lane & 15);
    #pragma unroll
    for (int r = 0; r < 4; ++r) {
        Pb[(size_t)(orow + r) * N + ocol]           = acc00[r];
        Pb[(size_t)(orow + r) * N + ocol + 16]      = acc01[r];
        Pb[(size_t)(orow + 16 + r) * N + ocol]      = acc10[r];
        Pb[(size_t)(orow + 16 + r) * N + ocol + 16] = acc11[r];
    }
}

// O = fp32( fp16( fp16( (sum of SPL partials) * scale[n] ) + bias[n] ) )
template <int SPL>
__global__ __launch_bounds__(256)
void fp6lin_finalize(const float* __restrict__ P,
                     const float* __restrict__ S,
                     const float* __restrict__ Bi,
                     float* __restrict__ O)
{
    const size_t i = ((size_t)blockIdx.x * 256 + threadIdx.x) * 4;
    const int n = (int)(i & (N - 1));
    float4 v = *(const float4*)(P + i);
    #pragma unroll
    for (int s = 1; s < SPL; ++s) {
        float4 u = *(const float4*)(P + (size_t)s * M * N + i);
        v.x += u.x; v.y += u.y; v.z += u.z; v.w += u.w;
    }
    float4 sc = *(const float4*)(S + n);
    float4 bb = *(const float4*)(Bi + n);
    v.x = (float)(_Float16)((float)(_Float16)(v.x * sc.x) + bb.x);
    v.y = (float)(_Float16)((float)(_Float16)(v.y * sc.y) + bb.y);
    v.z = (float)(_Float16)((float)(_Float16)(v.z * sc.z) + bb.z);
    v.w = (float)(_Float16)((float)(_Float16)(v.w * sc.w) + bb.w);
    *(float4*)(O + i) = v;
}

extern "C" void kernel_launch(void* const* d_in, const int* in_sizes, int n_in,
                              void* d_out, int out_size, void* d_ws, size_t ws_size,
                              hipStream_t stream) {
    const float* x  = (const float*)d_in[0];
    const float* w  = (const float*)d_in[1];
    const float* s  = (const float*)d_in[2];
    const float* bi = (const float*)d_in[3];
    float* o  = (float*)d_out;
    float* ws = (float*)d_ws;

    const size_t slice = (size_t)M * N * sizeof(float);   // 4 MB
    const int fin_grid = M * N / 4 / 256;                 // 1024

    if (ws_size >= 4 * slice) {
        fp6lin_gemm<4><<<dim3(4 * 64 * 4), dim3(256), 0, stream>>>(x, w, ws);
        fp6lin_finalize<4><<<dim3(fin_grid), dim3(256), 0, stream>>>(ws, s, bi, o);
    } else if (ws_size >= 2 * slice) {
        fp6lin_gemm<2><<<dim3(4 * 64 * 2), dim3(256), 0, stream>>>(x, w, ws);
        fp6lin_finalize<2><<<dim3(fin_grid), dim3(256), 0, stream>>>(ws, s, bi, o);
    } else {
        fp6lin_gemm<1><<<dim3(4 * 64), dim3(256), 0, stream>>>(x, w, o);
        fp6lin_finalize<1><<<dim3(fin_grid), dim3(256), 0, stream>>>(o, s, bi, o);
    }
}